// Round 10
// baseline (881.316 us; speedup 1.0000x reference)
//
#include <hip/hip_runtime.h>
#include <hip/hip_bf16.h>

typedef unsigned int u32;
typedef unsigned long long u64;
typedef _Float16     f16;
typedef f16   f16x8v __attribute__((ext_vector_type(8)));
typedef f16   f16x4v __attribute__((ext_vector_type(4)));
typedef float f32x4  __attribute__((ext_vector_type(4)));

#define GX_BYTES ((size_t)65536 * 1024 * 2)

__device__ __forceinline__ float sigm(float x) {
    return __builtin_amdgcn_rcpf(1.0f + __expf(-x));
}
__device__ __forceinline__ float tanh_f(float x) {
    return 1.0f - 2.0f * __builtin_amdgcn_rcpf(__expf(2.0f * x) + 1.0f);
}
__device__ __forceinline__ f16x8v pack8(float4 a, float4 b) {
    f16x8v v;
    v[0] = (f16)a.x; v[1] = (f16)a.y; v[2] = (f16)a.z; v[3] = (f16)a.w;
    v[4] = (f16)b.x; v[5] = (f16)b.y; v[6] = (f16)b.z; v[7] = (f16)b.w;
    return v;
}

// ---------------------------------------------------------------------------
// Kernel 1: gates_x in INTERLEAVED layout gx[m][unit*4+gate], with B rows
// interleaved so stores stay CONTIGUOUS (round-9's scattered-store fix):
// wgy in [0,8) covers units [32*wgy, 32*wgy+32); B-tile row rb maps to
// (unit = 32*wgy + rb>>2, gate = rb&3), so output col nl == interleaved col
// wgy*128+nl and the store code is byte-identical to the round-5 version.
// Also zeroes the 256 KB mailbox each replay (stale-tag protection).
// ---------------------------------------------------------------------------
__global__ __launch_bounds__(256) void gemm_gx(
    const float* __restrict__ X,
    const float* __restrict__ Wf, const float* __restrict__ Wi,
    const float* __restrict__ Wc, const float* __restrict__ Wo,
    const float* __restrict__ bf_, const float* __restrict__ bi_,
    const float* __restrict__ bc_, const float* __restrict__ bo_,
    f16* __restrict__ gx, u32* __restrict__ hx) {
    __shared__ _Float16 As[128 * 40];
    __shared__ _Float16 Bs[128 * 40];
    __shared__ float bias_lds[128];

    const int tid = threadIdx.x;
    const int wgy = blockIdx.y;          // unit-block [32*wgy, 32*wgy+32)
    const size_t m0 = (size_t)blockIdx.x * 128;

    if (wgy == 0) {
        const int gid = blockIdx.x * 256 + tid;
        if (gid < 16384) {
            int4 z; z.x = 0; z.y = 0; z.z = 0; z.w = 0;
            ((int4*)hx)[gid] = z;
        }
    }

    const float* Wsel[4] = {Wf, Wi, Wc, Wo};
    const float* bsel[4] = {bf_, bi_, bc_, bo_};

    if (tid < 128)
        bias_lds[tid] = bsel[tid & 3][wgy * 32 + (tid >> 2)];

    const int r  = tid >> 2;             // B-tile row this thread loads
    const int c8 = (tid & 3) * 8;

    const float* Ap0 = X + (m0 + r) * 256 + c8;
    const float* Ap1 = Ap0 + 64 * 256;
    // B row rb -> gate rb&3, unit 32*wgy + (rb>>2); rows r and r+64 share gate
    const float* Bp0 = Wsel[r & 3] + (size_t)(wgy * 32 + (r >> 2)) * 512 + c8;
    const float* Bp1 = Bp0 + 16 * 512;   // unit + 16

    const int lane = tid & 63;
    const int w    = tid >> 6;
    const int wm = w >> 1, wn = w & 1;
    const int col = lane & 15, quad = lane >> 4;

    f32x4 acc[4][4] = {};

    for (int kc = 0; kc < 8; kc++) {
        const int kk = kc * 32;
        float4 a00 = *(const float4*)(Ap0 + kk);
        float4 a01 = *(const float4*)(Ap0 + kk + 4);
        float4 a10 = *(const float4*)(Ap1 + kk);
        float4 a11 = *(const float4*)(Ap1 + kk + 4);
        float4 b00 = *(const float4*)(Bp0 + kk);
        float4 b01 = *(const float4*)(Bp0 + kk + 4);
        float4 b10 = *(const float4*)(Bp1 + kk);
        float4 b11 = *(const float4*)(Bp1 + kk + 4);
        __syncthreads();
        *(f16x8v*)&As[r * 40 + c8]        = pack8(a00, a01);
        *(f16x8v*)&As[(r + 64) * 40 + c8] = pack8(a10, a11);
        *(f16x8v*)&Bs[r * 40 + c8]        = pack8(b00, b01);
        *(f16x8v*)&Bs[(r + 64) * 40 + c8] = pack8(b10, b11);
        __syncthreads();
        f16x8v a[4], b[4];
        #pragma unroll
        for (int i = 0; i < 4; i++)
            a[i] = *(const f16x8v*)&As[(wm * 64 + i * 16 + col) * 40 + quad * 8];
        #pragma unroll
        for (int j = 0; j < 4; j++)
            b[j] = *(const f16x8v*)&Bs[(wn * 64 + j * 16 + col) * 40 + quad * 8];
        #pragma unroll
        for (int i = 0; i < 4; i++)
            #pragma unroll
            for (int j = 0; j < 4; j++)
                acc[i][j] = __builtin_amdgcn_mfma_f32_16x16x32_f16(a[i], b[j], acc[i][j], 0, 0, 0);
    }

    #pragma unroll
    for (int i = 0; i < 4; i++) {
        #pragma unroll
        for (int j = 0; j < 4; j++) {
            #pragma unroll
            for (int rg = 0; rg < 4; rg++) {
                const size_t m = m0 + wm * 64 + i * 16 + quad * 4 + rg;
                const int nl = wn * 64 + j * 16 + col;
                gx[m * 1024 + (size_t)wgy * 128 + nl] = (f16)(acc[i][j][rg] + bias_lds[nl]);
            }
        }
    }
}

// ---------------------------------------------------------------------------
// Kernel 2: 2-batch M-packed recurrence, gate-per-tile N layout.
// 256 WGs x 256 thr (4 waves, 1 wave/SIMD). WG (p = bb>>2, j = bb&3) owns
// batches {2p,2p+1}, units [64j,64j+64). M = 16 rows = batch(row>>3) x 8
// replicas -> MFMA halves vs round 9: wave w = 16 units x 4 gate-tiles x
// 8 kt = 32 MFMA/step (620 cyc/SIMD vs 1242).
// Lane mapping: A row = l15 -> lane supplies h[batch l15>>3] (b128,
// 2-way bank alias = free); C reg0 = row quad*4 -> batch quad>>1, so each
// lane holds ONE cell's F,I,G,O in acc[0..3][0] — single elementwise
// chain, no DPP recombine, no gates-LDS (round-7's two regressions gone).
//
// Exchange: champion protocol (tagged words (h<<16)|(t+1), relaxed agent
// atomics, 2-slot double buffer, early-issue at step top, check after
// phase A = own-quarter kt, tight spin on mismatch, bounded). Fan-in 3,
// 192 pollers/WG each loading ONE u64 (two unit-adjacent words of one
// batch) and staging one packed u32 into LDS. Publish: quads 0,2 (one
// writer per cell). Reuse induction holds for any peer set: a peer
// publishes tag t+1 only after it consumed ALL our tag-t words. Mailbox
// [pair][slot][batch][256] = 256 KB, zeroed each replay by gemm_gx;
// t=0 poll matches the zeroed tag-0 words (= h_0). Same gx/weights/kt
// conventions as round 9 otherwise.
// ---------------------------------------------------------------------------
__global__ __launch_bounds__(256) void lstm_rec(
    const float* __restrict__ Wf, const float* __restrict__ Wi,
    const float* __restrict__ Wc, const float* __restrict__ Wo,
    const f16* __restrict__ gx,
    const float* __restrict__ Wout, const float* __restrict__ bout,
    u32* hx,
    float* __restrict__ out) {
    __shared__ _Float16 hbuf[2][2][256] __attribute__((aligned(16)));

    const int tid  = threadIdx.x;
    const int bb   = blockIdx.x;
    const int p    = bb >> 2;         // batch pair {2p, 2p+1}
    const int j    = bb & 3;          // unit-quarter 0..3
    const int w    = tid >> 6;        // wave 0..3
    const int l    = tid & 63;
    const int l15  = l & 15;
    const int quad = l >> 4;
    const int arow = l15 >> 3;        // batch whose h this lane supplies (A)
    const int bl   = quad >> 1;       // batch whose cell this lane owns (C)

    const int u = 64 * j + 16 * w + l15;   // this lane's unit

    // kt order: own quarter first (phase A), then remote quarters
    int ktm[8];
    ktm[0] = 2 * j; ktm[1] = 2 * j + 1;
    #pragma unroll
    for (int r = 0; r < 3; r++) {
        const int qr = (j + 1 + r) & 3;
        ktm[2 + 2 * r] = 2 * qr;
        ktm[3 + 2 * r] = 2 * qr + 1;
    }

    // --- register-resident B fragments (static reg indices; ktm only in
    //     addresses — rule #20) ---
    f16x8v wB[4][8];
    {
        const float* gp[4] = {Wf, Wi, Wc, Wo};
        #pragma unroll
        for (int g = 0; g < 4; g++) {
            const float* row = gp[g] + (size_t)u * 512 + 256 + quad * 8;
            #pragma unroll
            for (int idx = 0; idx < 8; idx++) {
                const int ko = ktm[idx] * 32;
                float4 x0 = *(const float4*)(row + ko);
                float4 x1 = *(const float4*)(row + ko + 4);
                wB[g][idx] = pack8(x0, x1);
            }
        }
    }

    // h_0 = 0 (1024 f16 = 512 u32)
    ((u32*)hbuf)[tid] = 0u;
    ((u32*)hbuf)[tid + 256] = 0u;

    u32* mail = hx + (size_t)p * 1024;   // [slot(2)][batch(2)][unit(256)]

    // poller assignment: tids 0..191 each own one u64 = units (ru, ru+1)
    // of batch pB in the 3 remote quarters.
    const int pollme = (tid < 192);
    const int pB  = tid / 96;                       // batch 0/1
    const int pi2 = (tid % 96) * 2;                 // even remote-unit rank
    const int ru  = pi2 + (pi2 >= 64 * j ? 64 : 0); // skip own quarter
    const size_t poff = (size_t)pB * 256 + ru;      // + slot*512

    // interleaved gx: lane's 4 gate values for (batch bl, unit u)
    const f16* gxr = gx + (size_t)(2 * p + bl) * 512 * 1024 + (size_t)u * 4;
    f16x4v gv = *(const f16x4v*)gxr;                 // t = 0
    float pf = (float)gv[0], pi_ = (float)gv[1];
    float pg = (float)gv[2], po  = (float)gv[3];

    float c = 0.0f;
    const f32x4 Zc = {0.f, 0.f, 0.f, 0.f};

    __syncthreads();   // h_0 visible

    for (int t = 0; t < 512; t++) {
        const int cur = t & 1;
        const int nxt = cur ^ 1;

        // 1. EARLY-ISSUE the remote u64 (checked after phase A)
        u64 rv = 0;
        if (pollme)
            rv = __hip_atomic_load((const u64*)(mail + cur * 512 + poff),
                                   __ATOMIC_RELAXED, __HIP_MEMORY_SCOPE_AGENT);

        // 2. gx prefetch for next step (one 8 B load)
        f16x4v gn = *(const f16x4v*)(gxr + (size_t)(t < 511 ? t + 1 : 511) * 1024);

        // 3. Phase A: own-quarter kt (no remote dependence)
        const _Float16* hA = &hbuf[cur][arow][quad * 8];
        f32x4 acc[4];
        {
            f16x8v A = *(const f16x8v*)&hA[ktm[0] * 32];
            #pragma unroll
            for (int g = 0; g < 4; g++)
                acc[g] = __builtin_amdgcn_mfma_f32_16x16x32_f16(A, wB[g][0], Zc, 0, 0, 0);
            f16x8v B = *(const f16x8v*)&hA[ktm[1] * 32];
            #pragma unroll
            for (int g = 0; g < 4; g++)
                acc[g] = __builtin_amdgcn_mfma_f32_16x16x32_f16(B, wB[g][1], acc[g], 0, 0, 0);
        }

        // 4. Check the early u64; tight spin only on mismatch; stage 1 u32.
        if (pollme) {
            const u32 want = (u32)t;
            int spin = 0;
            while ((((u32)rv & 0xFFFFu) != want ||
                    (((u32)(rv >> 32)) & 0xFFFFu) != want) && ++spin < (1 << 20))
                rv = __hip_atomic_load((const u64*)(mail + cur * 512 + poff),
                                       __ATOMIC_RELAXED, __HIP_MEMORY_SCOPE_AGENT);
            const u32 packed = (u32)((rv >> 16) & 0xFFFFu)
                             | (u32)(((rv >> 48) & 0xFFFFu) << 16);
            *(u32*)&hbuf[cur][pB][ru] = packed;
        }
        __syncthreads();   // remote three-quarters of h_t staged

        // 5. Phase B: remote kt
        #pragma unroll
        for (int idx = 2; idx < 8; idx++) {
            f16x8v A = *(const f16x8v*)&hA[ktm[idx] * 32];
            #pragma unroll
            for (int g = 0; g < 4; g++)
                acc[g] = __builtin_amdgcn_mfma_f32_16x16x32_f16(A, wB[g][idx], acc[g], 0, 0, 0);
        }

        // 6. Elementwise: lane's cell = (batch bl, unit u); reg 0 of each
        //    gate-tile is this cell's value (row = quad*4 -> batch quad>>1).
        float F = pf + acc[0][0];
        float I = pi_ + acc[1][0];
        float G = pg + acc[2][0];
        float O = po + acc[3][0];
        float sf = sigm(F), si = sigm(I), so = sigm(O);
        float tg = tanh_f(G);
        c = c * sf + si * tg;
        float h = tanh_f(c) * so;

        const f16 h16v = (f16)h;
        if ((quad & 1) == 0) {          // one writer per cell (quads 0, 2)
            u32 word = ((u32)__builtin_bit_cast(unsigned short, h16v) << 16)
                     | (u32)(t + 1);
            __hip_atomic_store(mail + nxt * 512 + bl * 256 + u, word,
                               __ATOMIC_RELAXED, __HIP_MEMORY_SCOPE_AGENT);
            hbuf[nxt][bl][u] = h16v;    // own quarter for next step
        }

        pf = (float)gn[0]; pi_ = (float)gn[1];
        pg = (float)gn[2]; po  = (float)gn[3];

        __syncthreads();   // own quarter of h_{t+1} visible; guards reuse
    }

    // Complete h_512 (slot 0, tag 512): own quarter already in hbuf[0].
    if (pollme) {
        u64 rv = __hip_atomic_load((const u64*)(mail + 0 * 512 + poff),
                                   __ATOMIC_RELAXED, __HIP_MEMORY_SCOPE_AGENT);
        int spin = 0;
        while ((((u32)rv & 0xFFFFu) != 512u ||
                (((u32)(rv >> 32)) & 0xFFFFu) != 512u) && ++spin < (1 << 20))
            rv = __hip_atomic_load((const u64*)(mail + 0 * 512 + poff),
                                   __ATOMIC_RELAXED, __HIP_MEMORY_SCOPE_AGENT);
        const u32 packed = (u32)((rv >> 16) & 0xFFFFu)
                         | (u32)(((rv >> 48) & 0xFFFFu) << 16);
        *(u32*)&hbuf[0][pB][ru] = packed;
    }
    __syncthreads();

    // out[2p+B, 32j:32j+32] = h_512 @ Wout^T + bout
    if (tid < 64) {
        const int B = tid >> 5;
        const int o = 32 * j + (tid & 31);
        float accv = bout[o];
        const _Float16* hr = &hbuf[0][B][0];
        const float* wr = Wout + (size_t)o * 256;
        for (int k0 = 0; k0 < 256; k0 += 8) {
            f16x8v hv = *(const f16x8v*)&hr[k0];
            float4 w0 = *(const float4*)(wr + k0);
            float4 w1 = *(const float4*)(wr + k0 + 4);
            accv += w0.x * (float)hv[0] + w0.y * (float)hv[1]
                  + w0.z * (float)hv[2] + w0.w * (float)hv[3]
                  + w1.x * (float)hv[4] + w1.y * (float)hv[5]
                  + w1.z * (float)hv[6] + w1.w * (float)hv[7];
        }
        out[(size_t)(2 * p + B) * 128 + o] = accv;
    }
}

extern "C" void kernel_launch(void* const* d_in, const int* in_sizes, int n_in,
                              void* d_out, int out_size, void* d_ws, size_t ws_size,
                              hipStream_t stream) {
    const float* x    = (const float*)d_in[0];
    const float* Wf   = (const float*)d_in[1];
    const float* bfv  = (const float*)d_in[2];
    const float* Wi   = (const float*)d_in[3];
    const float* biv  = (const float*)d_in[4];
    const float* Wc   = (const float*)d_in[5];
    const float* bcv  = (const float*)d_in[6];
    const float* Wo   = (const float*)d_in[7];
    const float* bov  = (const float*)d_in[8];
    const float* Wout = (const float*)d_in[9];
    const float* bout = (const float*)d_in[10];

    f16* gx = (f16*)d_ws;
    u32* hx = (u32*)((char*)d_ws + GX_BYTES);   // 256 KB mailbox after gx

    gemm_gx<<<dim3(512, 8), 256, 0, stream>>>(x, Wf, Wi, Wc, Wo, bfv, biv, bcv, bov, gx, hx);
    lstm_rec<<<256, 256, 0, stream>>>(Wf, Wi, Wc, Wo, gx, Wout, bout, hx, (float*)d_out);
}

// Round 11
// 723.514 us; speedup vs baseline: 1.2181x; 1.2181x over previous
//
#include <hip/hip_runtime.h>
#include <hip/hip_bf16.h>

typedef unsigned int u32;
typedef _Float16     f16;
typedef f16   f16x8v __attribute__((ext_vector_type(8)));
typedef f16   f16x4v __attribute__((ext_vector_type(4)));
typedef float f32x4  __attribute__((ext_vector_type(4)));

#define GX_BYTES ((size_t)65536 * 1024 * 2)

__device__ __forceinline__ float sigm(float x) {
    return __builtin_amdgcn_rcpf(1.0f + __expf(-x));
}
__device__ __forceinline__ float tanh_f(float x) {
    return 1.0f - 2.0f * __builtin_amdgcn_rcpf(__expf(2.0f * x) + 1.0f);
}
__device__ __forceinline__ f16x8v pack8(float4 a, float4 b) {
    f16x8v v;
    v[0] = (f16)a.x; v[1] = (f16)a.y; v[2] = (f16)a.z; v[3] = (f16)a.w;
    v[4] = (f16)b.x; v[5] = (f16)b.y; v[6] = (f16)b.z; v[7] = (f16)b.w;
    return v;
}

// ---------------------------------------------------------------------------
// Kernel 1: gates_x -> INTERLEAVED gx[m][unit*4+gate], at round-5 cost.
// Block (wgy) covers units [32*wgy, 32*wgy+32) x all 4 gates (128 B-rows).
// The interleave is done INSIDE LDS (permuted Bs rows), so BOTH global
// sides stay contiguous:
//   - B loads: wave g loads gate g's rows, 64 B/thread contiguous
//     (round-9's scattered-store and round-10's scattered-load mistakes
//     both avoided).
//   - B-row (u_l, g) stored at PHYSICAL Bs row P = u_l + 32g, address
//     P*40 + (P>>5)*8 (+8 f16 skew per gate block, keeps 16 B alignment,
//     spreads fragment-read banks).
//   - MFMA b-fragment for output col c reads phys row (c>>2) + ((c&3)<<5):
//     output cols emerge in interleaved (unit*4+gate) order, so the
//     epilogue store gx[m*1024 + wgy*128 + nl] is contiguous AND lands in
//     the interleaved layout lstm_rec wants.
// Also zeroes the 256 KB mailbox each replay (stale-tag protection).
// ---------------------------------------------------------------------------
__global__ __launch_bounds__(256) void gemm_gx(
    const float* __restrict__ X,
    const float* __restrict__ Wf, const float* __restrict__ Wi,
    const float* __restrict__ Wc, const float* __restrict__ Wo,
    const float* __restrict__ bf_, const float* __restrict__ bi_,
    const float* __restrict__ bc_, const float* __restrict__ bo_,
    f16* __restrict__ gx, u32* __restrict__ hx) {
    __shared__ _Float16 As[128 * 40];
    __shared__ _Float16 Bs[128 * 40 + 32];
    __shared__ float bias_lds[128];

    const int tid = threadIdx.x;
    const int wgy = blockIdx.y;              // unit-block [32*wgy, 32*wgy+32)
    const size_t m0 = (size_t)blockIdx.x * 128;

    if (wgy == 0) {
        const int gid = blockIdx.x * 256 + tid;
        if (gid < 16384) {
            int4 z; z.x = 0; z.y = 0; z.z = 0; z.w = 0;
            ((int4*)hx)[gid] = z;
        }
    }

    const float* Wsel[4] = {Wf, Wi, Wc, Wo};
    const float* bsel[4] = {bf_, bi_, bc_, bo_};

    // bias_lds[c] = bias of (unit 32*wgy + c>>2, gate c&3)
    if (tid < 128) bias_lds[tid] = bsel[tid & 3][wgy * 32 + (tid >> 2)];

    // A loader (round-5 mapping: 2 rows x 8 cols per thread)
    const int rA  = tid >> 2;
    const int c8A = (tid & 3) * 8;
    const float* Ap0 = X + (m0 + rA) * 256 + c8A;
    const float* Ap1 = Ap0 + 64 * 256;

    // B loader: wave gB covers gate gB; thread = (unit-in-block, k-half).
    const int gB    = tid >> 6;              // 0..3
    const int subB  = tid & 63;
    const int rowlB = subB >> 1;             // 0..31
    const int khB   = subB & 1;              // 16-col half
    const float* BpG = Wsel[gB] + (size_t)(wgy * 32 + rowlB) * 512 + khB * 16;
    const int RB = rowlB + 32 * gB;          // phys Bs row; (RB>>5) == gB
    _Float16* BsW = &Bs[RB * 40 + gB * 8 + khB * 16];

    const int lane = tid & 63;
    const int w    = tid >> 6;
    const int wm = w >> 1, wn = w & 1;
    const int col = lane & 15, quad = lane >> 4;

    f32x4 acc[4][4] = {};

    for (int kc = 0; kc < 8; kc++) {
        const int kk = kc * 32;
        float4 a00 = *(const float4*)(Ap0 + kk);
        float4 a01 = *(const float4*)(Ap0 + kk + 4);
        float4 a10 = *(const float4*)(Ap1 + kk);
        float4 a11 = *(const float4*)(Ap1 + kk + 4);
        float4 b0  = *(const float4*)(BpG + kk);
        float4 b1  = *(const float4*)(BpG + kk + 4);
        float4 b2  = *(const float4*)(BpG + kk + 8);
        float4 b3  = *(const float4*)(BpG + kk + 12);
        __syncthreads();
        *(f16x8v*)&As[rA * 40 + c8A]        = pack8(a00, a01);
        *(f16x8v*)&As[(rA + 64) * 40 + c8A] = pack8(a10, a11);
        *(f16x8v*)&BsW[0] = pack8(b0, b1);
        *(f16x8v*)&BsW[8] = pack8(b2, b3);
        __syncthreads();
        f16x8v a[4], b[4];
        #pragma unroll
        for (int i = 0; i < 4; i++)
            a[i] = *(const f16x8v*)&As[(wm * 64 + i * 16 + col) * 40 + quad * 8];
        #pragma unroll
        for (int jdx = 0; jdx < 4; jdx++) {
            const int cB = wn * 64 + jdx * 16 + col;          // output col
            const int R  = (cB >> 2) + ((cB & 3) << 5);       // phys row
            b[jdx] = *(const f16x8v*)&Bs[R * 40 + (R >> 5) * 8 + quad * 8];
        }
        #pragma unroll
        for (int i = 0; i < 4; i++)
            #pragma unroll
            for (int jdx = 0; jdx < 4; jdx++)
                acc[i][jdx] = __builtin_amdgcn_mfma_f32_16x16x32_f16(a[i], b[jdx], acc[i][jdx], 0, 0, 0);
    }

    #pragma unroll
    for (int i = 0; i < 4; i++) {
        #pragma unroll
        for (int jdx = 0; jdx < 4; jdx++) {
            #pragma unroll
            for (int rg = 0; rg < 4; rg++) {
                const size_t m = m0 + wm * 64 + i * 16 + quad * 4 + rg;
                const int nl = wn * 64 + jdx * 16 + col;
                gx[m * 1024 + (size_t)wgy * 128 + nl] = (f16)(acc[i][jdx][rg] + bias_lds[nl]);
            }
        }
    }
}

// ---------------------------------------------------------------------------
// Kernel 2: BYTE-IDENTICAL to round 9's champion (567 us proven).
// Pairwise recurrence + K-split pipeline + early-issued quad0-only poll +
// vectorized interleaved gx. 256 WGs x 512 thr, 2 waves/SIMD.
// ---------------------------------------------------------------------------
__global__ __launch_bounds__(512, 2) void lstm_rec(
    const float* __restrict__ Wf, const float* __restrict__ Wi,
    const float* __restrict__ Wc, const float* __restrict__ Wo,
    const f16* __restrict__ gx,
    const float* __restrict__ Wout, const float* __restrict__ bout,
    u32* hx,
    float* __restrict__ out) {
    __shared__ _Float16 hbuf[2][256] __attribute__((aligned(16)));

    const int tid  = threadIdx.x;
    const int bb   = blockIdx.x;
    const int b    = bb & 127;          // batch
    const int s    = bb >> 7;           // unit-half 0/1
    const int w    = tid >> 6;          // wave 0..7
    const int l    = tid & 63;
    const int l15  = l & 15;
    const int quad = l >> 4;

    const int u_loc = 16 * w + l15;     // 0..127 within our half
    const int u     = 128 * s + u_loc;  // absolute unit

    const int kOwn = 128 * s;           // h-column base of own half
    const int kRem = 128 * (1 - s);     // h-column base of remote half

    // --- register-resident B fragments, STATIC indices ---
    f16x8v wB[4][8];
    {
        const float* gp[4] = {Wf, Wi, Wc, Wo};
        #pragma unroll
        for (int g = 0; g < 4; g++) {
            const float* rowO = gp[g] + (size_t)u * 512 + 256 + kOwn + quad * 8;
            const float* rowR = gp[g] + (size_t)u * 512 + 256 + kRem + quad * 8;
            #pragma unroll
            for (int k = 0; k < 4; k++) {
                float4 x0 = *(const float4*)(rowO + k * 32);
                float4 x1 = *(const float4*)(rowO + k * 32 + 4);
                wB[g][k] = pack8(x0, x1);
                float4 y0 = *(const float4*)(rowR + k * 32);
                float4 y1 = *(const float4*)(rowR + k * 32 + 4);
                wB[g][4 + k] = pack8(y0, y1);
            }
        }
    }

    float c = 0.0f;
    if (tid < 256) hbuf[0][tid] = (f16)0.0f;   // h_0 = 0 (both halves)

    u32* pub = hx + (size_t)b * 512 + (size_t)s * 256;        // + slot*128 + u_loc
    u32* par = hx + (size_t)b * 512 + (size_t)(1 - s) * 256;  // partner's words

    // interleaved gx: lane's 4 gate values are 8 contiguous bytes
    const f16* gxr = gx + (size_t)b * 512 * 1024 + (size_t)u * 4;
    f16x4v gv = *(const f16x4v*)gxr;                 // t = 0
    float pf = (float)gv[0], pi_ = (float)gv[1];
    float pg = (float)gv[2], po  = (float)gv[3];

    const f32x4 Zc = {0.f, 0.f, 0.f, 0.f};

    __syncthreads();   // h_0 visible

    for (int t = 0; t < 512; t++) {
        const int cur = t & 1;
        const int nxt = cur ^ 1;

        // 1. EARLY-ISSUE the partner-word load — quad0 lanes only (the
        //    writers). 4x fewer LLC requests than all-lane polling.
        u32 rw = 0;
        if (quad == 0)
            rw = __hip_atomic_load(par + cur * 128 + u_loc,
                                   __ATOMIC_RELAXED, __HIP_MEMORY_SCOPE_AGENT);

        // 2. gx prefetch for next step (one 8 B load)
        f16x4v gn = *(const f16x4v*)(gxr + (size_t)(t < 511 ? t + 1 : 511) * 1024);

        // 3. Phase A: own-K contribution (no remote dependence)
        const _Float16* hOwn = &hbuf[cur][kOwn + quad * 8];
        f32x4 acc[4];
        #pragma unroll
        for (int k = 0; k < 4; k++) {
            f16x8v A = *(const f16x8v*)&hOwn[k * 32];
            if (k == 0) {
                #pragma unroll
                for (int g = 0; g < 4; g++)
                    acc[g] = __builtin_amdgcn_mfma_f32_16x16x32_f16(A, wB[g][0], Zc, 0, 0, 0);
            } else {
                #pragma unroll
                for (int g = 0; g < 4; g++)
                    acc[g] = __builtin_amdgcn_mfma_f32_16x16x32_f16(A, wB[g][k], acc[g], 0, 0, 0);
            }
        }

        // 4. Check the early load; tight spin only on mismatch (quad0 only;
        //    t=0 matches the zeroed mailbox's tag-0 words -> stages h_0=0).
        if (quad == 0) {
            const u32 want = (u32)t;
            int spin = 0;
            while ((rw & 0xFFFFu) != want && ++spin < (1 << 20))
                rw = __hip_atomic_load(par + cur * 128 + u_loc,
                                       __ATOMIC_RELAXED, __HIP_MEMORY_SCOPE_AGENT);
            hbuf[cur][kRem + u_loc] =
                __builtin_bit_cast(_Float16, (unsigned short)(rw >> 16));
        }
        __syncthreads();   // remote half of h_t staged

        // 5. Phase B: remote-K contribution
        const _Float16* hRem = &hbuf[cur][kRem + quad * 8];
        #pragma unroll
        for (int k = 0; k < 4; k++) {
            f16x8v A = *(const f16x8v*)&hRem[k * 32];
            #pragma unroll
            for (int g = 0; g < 4; g++)
                acc[g] = __builtin_amdgcn_mfma_f32_16x16x32_f16(A, wB[g][4 + k], acc[g], 0, 0, 0);
        }

        // 6. Elementwise (rows replicated -> reg 0 is this lane's unit)
        float F = pf + acc[0][0];
        float I = pi_ + acc[1][0];
        float G = pg + acc[2][0];
        float O = po + acc[3][0];
        float sf = sigm(F), si = sigm(I), so = sigm(O);
        float tg = tanh_f(G);
        c = c * sf + si * tg;
        float h = tanh_f(c) * so;

        const f16 h16v = (f16)h;
        if (quad == 0) {
            u32 word = ((u32)__builtin_bit_cast(unsigned short, h16v) << 16)
                     | (u32)(t + 1);
            __hip_atomic_store(pub + nxt * 128 + u_loc, word,
                               __ATOMIC_RELAXED, __HIP_MEMORY_SCOPE_AGENT);
            hbuf[nxt][u] = h16v;    // own half for next step
        }

        pf = (float)gn[0]; pi_ = (float)gn[1];
        pg = (float)gn[2]; po  = (float)gn[3];

        __syncthreads();   // own half of h_{t+1} visible; guards hbuf reuse
    }

    // Complete h_512: own half is in hbuf[0]; poll partner's tag-512 words.
    if (quad == 0) {
        u32 rw = __hip_atomic_load(par + 0 * 128 + u_loc,
                                   __ATOMIC_RELAXED, __HIP_MEMORY_SCOPE_AGENT);
        int spin = 0;
        while ((rw & 0xFFFFu) != 512u && ++spin < (1 << 20))
            rw = __hip_atomic_load(par + 0 * 128 + u_loc,
                                   __ATOMIC_RELAXED, __HIP_MEMORY_SCOPE_AGENT);
        hbuf[0][kRem + u_loc] =
            __builtin_bit_cast(_Float16, (unsigned short)(rw >> 16));
    }
    __syncthreads();

    // out[b, 64s:64s+64] = h_512 @ Wout^T + bout (both WGs have full h_512)
    if (tid < 64) {
        const int o = 64 * s + tid;
        float accv = bout[o];
        const float4* wv = (const float4*)(Wout + (size_t)o * 256);
        #pragma unroll
        for (int q = 0; q < 64; q++) {
            float4 v = wv[q];
            accv += v.x * (float)hbuf[0][q * 4 + 0];
            accv += v.y * (float)hbuf[0][q * 4 + 1];
            accv += v.z * (float)hbuf[0][q * 4 + 2];
            accv += v.w * (float)hbuf[0][q * 4 + 3];
        }
        out[(size_t)b * 128 + o] = accv;
    }
}

extern "C" void kernel_launch(void* const* d_in, const int* in_sizes, int n_in,
                              void* d_out, int out_size, void* d_ws, size_t ws_size,
                              hipStream_t stream) {
    const float* x    = (const float*)d_in[0];
    const float* Wf   = (const float*)d_in[1];
    const float* bfv  = (const float*)d_in[2];
    const float* Wi   = (const float*)d_in[3];
    const float* biv  = (const float*)d_in[4];
    const float* Wc   = (const float*)d_in[5];
    const float* bcv  = (const float*)d_in[6];
    const float* Wo   = (const float*)d_in[7];
    const float* bov  = (const float*)d_in[8];
    const float* Wout = (const float*)d_in[9];
    const float* bout = (const float*)d_in[10];

    f16* gx = (f16*)d_ws;
    u32* hx = (u32*)((char*)d_ws + GX_BYTES);   // 256 KB mailbox after gx

    gemm_gx<<<dim3(512, 8), 256, 0, stream>>>(x, Wf, Wi, Wc, Wo, bfv, biv, bcv, bov, gx, hx);
    lstm_rec<<<256, 512, 0, stream>>>(Wf, Wi, Wc, Wo, gx, Wout, bout, hx, (float*)d_out);
}